// Round 8
// baseline (217.967 us; speedup 1.0000x reference)
//
#include <hip/hip_runtime.h>

#define NN 384
#define CC 128
#define NPOS (NN * NN)  // 147456

typedef short bf8_t __attribute__((ext_vector_type(8)));
typedef float f32x4_t __attribute__((ext_vector_type(4)));

#define MFMA16(a, b, c) __builtin_amdgcn_mfma_f32_16x16x32_bf16((a), (b), (c), 0, 0, 0)

__device__ __forceinline__ unsigned short f2bf(float f) {
  unsigned int u = __builtin_bit_cast(unsigned int, f);
  u += 0x7fffu + ((u >> 16) & 1u);  // RNE
  return (unsigned short)(u >> 16);
}
// packed RNE f32x2 -> bf16x2 (low=a, high=b); bit-identical to f2bf
__device__ __forceinline__ unsigned int f2bf2(float a, float b) {
  unsigned int r;
  asm("v_cvt_pk_bf16_f32 %0, %1, %2" : "=v"(r) : "v"(a), "v"(b));
  return r;
}
__device__ __forceinline__ float bf2f(unsigned short s) {
  return __builtin_bit_cast(float, ((unsigned int)s) << 16);
}
__device__ __forceinline__ float sigm(float x) { return 1.0f / (1.0f + __expf(-x)); }

// ---------------- kW: fp32 -> bf16 weight concat [768][128] -----------------
__global__ __launch_bounds__(256) void kW(const float* __restrict__ a,
                                          const float* __restrict__ b,
                                          const float* __restrict__ c,
                                          const float* __restrict__ d,
                                          const float* __restrict__ e,
                                          const float* __restrict__ f,
                                          unsigned short* __restrict__ o) {
  int idx = (blockIdx.x * 256 + threadIdx.x) * 4;
  const float* s = f;
  if (idx < 16384) s = a;
  else if (idx < 32768) s = b;
  else if (idx < 49152) s = c;
  else if (idx < 65536) s = d;
  else if (idx < 81920) s = e;
  int off = idx & 16383;
  float4 v = *(const float4*)(s + off);
  uint2 w;
  w.x = f2bf2(v.x, v.y);
  w.y = f2bf2(v.z, v.w);
  *(uint2*)(o + idx) = w;
}

// ---------------- kLN: LN1 streaming, x2d fp32 -> x_ln bf16 [pos][c] --------
__global__ __launch_bounds__(256) void kLN(const float* __restrict__ x,
                                           const float* __restrict__ n1g,
                                           const float* __restrict__ n1b,
                                           unsigned short* __restrict__ x_ln) {
  int t = threadIdx.x;
  int pos = blockIdx.x * 128 + (t >> 1);
  int half = t & 1;
  const float* xr = x + (size_t)pos * CC + half * 64;
  float v[64];
  float s = 0.f;
#pragma unroll
  for (int a = 0; a < 16; ++a) {
    float4 f4 = ((const float4*)xr)[a];
    v[4 * a + 0] = f4.x; v[4 * a + 1] = f4.y;
    v[4 * a + 2] = f4.z; v[4 * a + 3] = f4.w;
    s += f4.x + f4.y + f4.z + f4.w;
  }
  s += __shfl_xor(s, 1);
  float mu = s * (1.0f / CC);
  float vs = 0.f;
#pragma unroll
  for (int a = 0; a < 64; ++a) { float d = v[a] - mu; vs += d * d; }
  vs += __shfl_xor(vs, 1);
  float rs = rsqrtf(vs * (1.0f / CC) + 1e-5f);
  unsigned short* dst = x_ln + (size_t)pos * CC + half * 64;
#pragma unroll
  for (int a8 = 0; a8 < 8; ++a8) {
    union { bf8_t v8; unsigned int w[4]; } u;
#pragma unroll
    for (int q = 0; q < 4; ++q) {
      int c0 = half * 64 + a8 * 8 + q * 2;
      float y0 = (v[a8 * 8 + q * 2 + 0] - mu) * rs * n1g[c0] + n1b[c0];
      float y1 = (v[a8 * 8 + q * 2 + 1] - mu) * rs * n1g[c0 + 1] + n1b[c0 + 1];
      u.w[q] = f2bf2(y0, y1);
    }
    *(bf8_t*)(dst + a8 * 8) = u.v8;
  }
}

// ---------------- kP: projections + gates, one small independent job/block --
// XCD-grouped mapping: the 6 jobs (p,h) of a pos-tile run on the SAME XCD,
// temporally adjacent -> x_ln tile fetched once per XCD L2 (R7: FETCH showed
// ~3x read amplification from round-robin XCD spread of same-tile jobs).
__global__ __launch_bounds__(256, 2) void kP(
    const unsigned short* __restrict__ x_ln, const unsigned short* __restrict__ wcat,
    const float* __restrict__ b1i, const float* __restrict__ b1is,
    const float* __restrict__ b1j, const float* __restrict__ b1js,
    const float* __restrict__ b3v, unsigned short* __restrict__ i_s,
    unsigned short* __restrict__ j_s, unsigned short* __restrict__ g3) {
  __shared__ __align__(16) unsigned short lds[16640];
  // [0,8192): Wv (later gather tile)  [8192,16384): Wg  [16384,16640): bias
  float* bl = (float*)(lds + 16384);

  int b = blockIdx.x;
  int xcd = b & 7, m = b >> 3;       // dispatch is round-robin across 8 XCDs
  int tl = m / 6, job = m % 6;       // 144 tiles/XCD x 6 jobs
  int pt = xcd * 144 + tl;
  int p = job >> 1, h = job & 1;
  int p0 = pt * 128;
  int t = threadIdx.x, lane = t & 63, wave = t >> 6;
  int lr = lane & 15, lh = lane >> 4;

  // ---- X fragments: direct global->reg (issued first, drain at barrier) ----
  bf8_t xf[2][4];
#pragma unroll
  for (int nt = 0; nt < 2; ++nt)
#pragma unroll
    for (int kk = 0; kk < 4; ++kk)
      xf[nt][kk] = *(const bf8_t*)(x_ln + (size_t)(p0 + wave * 32 + nt * 16 + lr) * CC +
                                   kk * 32 + lh * 8);

  // ---- W staging (pre-swizzled global source, linear LDS dest) ----
  int mV = p * 2;
  const unsigned short* Wv = wcat + (size_t)mV * CC * CC + h * 64 * CC;
#pragma unroll
  for (int it = 0; it < 4; ++it) {
    int u = it * 256 + t;
    int row = u >> 4, sl = u & 15;
    int slg = sl ^ (row & 7);
    __builtin_amdgcn_global_load_lds(
        (const __attribute__((address_space(1))) unsigned int*)(Wv + row * CC + slg * 8),
        (__attribute__((address_space(3))) unsigned int*)(lds + u * 8), 16, 0, 0);
  }
  if (p < 2) {
    const unsigned short* Wg = wcat + (size_t)(mV + 1) * CC * CC + h * 64 * CC;
#pragma unroll
    for (int it = 0; it < 4; ++it) {
      int u = it * 256 + t;
      int row = u >> 4, sl = u & 15;
      int slg = sl ^ (row & 7);
      __builtin_amdgcn_global_load_lds(
          (const __attribute__((address_space(1))) unsigned int*)(Wg + row * CC + slg * 8),
          (__attribute__((address_space(3))) unsigned int*)(lds + 8192 + u * 8), 16, 0, 0);
    }
  }
  // ---- bias: bl[0..63]=V, bl[64..127]=G ----
  {
    const float* bvp = (p == 0) ? b1i : (p == 1) ? b1j : b3v;
    if (t < 16) ((float4*)bl)[t] = ((const float4*)(bvp + h * 64))[t];
    if (p < 2 && t >= 16 && t < 32) {
      const float* bgp = (p == 0) ? b1is : b1js;
      ((float4*)bl)[t] = ((const float4*)(bgp + h * 64))[t - 16];
    }
  }
  __syncthreads();

  // ---- bias prefetch to registers (latency hidden under COMP's MFMAs) ----
  float blv[16], blg[16];
  if (p < 2) {
#pragma unroll
    for (int ct = 0; ct < 4; ++ct)
#pragma unroll
      for (int r = 0; r < 4; ++r) {
        blv[ct * 4 + r] = bl[ct * 16 + lh * 4 + r];
        blg[ct * 4 + r] = bl[64 + ct * 16 + lh * 4 + r];
      }
  } else {
#pragma unroll
    for (int ct = 0; ct < 4; ++ct) blv[ct] = bl[ct * 16 + lr];
  }

  // ---- COMP ----
  f32x4_t z4 = {0.f, 0.f, 0.f, 0.f};
  f32x4_t accV[2][4], accG[2][4];
#pragma unroll
  for (int nt = 0; nt < 2; ++nt)
#pragma unroll
    for (int ct = 0; ct < 4; ++ct) { accV[nt][ct] = z4; accG[nt][ct] = z4; }
#pragma unroll
  for (int ct = 0; ct < 4; ++ct)
#pragma unroll
    for (int kk = 0; kk < 4; ++kk) {
      int rv = ct * 16 + lr;
      int slot = (kk * 4 + lh) ^ (rv & 7);
      bf8_t wv = *(const bf8_t*)&lds[rv * 128 + slot * 8];
      if (p < 2) {
        bf8_t wg = *(const bf8_t*)&lds[8192 + rv * 128 + slot * 8];
#pragma unroll
        for (int nt = 0; nt < 2; ++nt) {
          accV[nt][ct] = MFMA16(wv, xf[nt][kk], accV[nt][ct]);  // D[c][pos]
          accG[nt][ct] = MFMA16(wg, xf[nt][kk], accG[nt][ct]);
        }
      } else {
#pragma unroll
        for (int nt = 0; nt < 2; ++nt)
          accV[nt][ct] = MFMA16(xf[nt][kk], wv, accV[nt][ct]);  // D[pos][c]
      }
    }
  __syncthreads();  // all waves done reading W -> lds[0,8192) becomes gather

  if (p < 2) {
    // gated, gather [64c][128pos] swizzled, store transposed 256B segments
#pragma unroll
    for (int nt = 0; nt < 2; ++nt)
#pragma unroll
      for (int ct = 0; ct < 4; ++ct) {
        int pos = wave * 32 + nt * 16 + lr;
        int sw = ((ct * 4 + lh) & 7) << 4;
        int px = pos ^ sw;
#pragma unroll
        for (int rp = 0; rp < 2; ++rp) {
          int r0 = rp * 2;
          int cl = ct * 16 + lh * 4 + r0;
          float o0 = (accV[nt][ct][r0] + blv[ct * 4 + r0]) *
                     sigm(accG[nt][ct][r0] + blg[ct * 4 + r0]);
          float o1 = (accV[nt][ct][r0 + 1] + blv[ct * 4 + r0 + 1]) *
                     sigm(accG[nt][ct][r0 + 1] + blg[ct * 4 + r0 + 1]);
          unsigned int pk = f2bf2(o0, o1);
          lds[cl * 128 + px] = (unsigned short)pk;
          lds[(cl + 1) * 128 + px] = (unsigned short)(pk >> 16);
        }
      }
    __syncthreads();
    unsigned short* dstm = p ? j_s : i_s;
#pragma unroll
    for (int it = 0; it < 4; ++it) {
      int u = it * 256 + t;
      int cl = u >> 4, ch = u & 15;
      int s = (cl >> 2) & 7;
      bf8_t v = *(const bf8_t*)&lds[cl * 128 + ((ch ^ (s << 1)) * 8)];
      *(bf8_t*)(dstm + (size_t)(h * 64 + cl) * NPOS + p0 + ch * 8) = v;
    }
  } else {
    // sigmoid only, gather [128pos][64c] swizzled, store natural 128B segments
#pragma unroll
    for (int nt = 0; nt < 2; ++nt)
#pragma unroll
      for (int ct = 0; ct < 4; ++ct) {
        int cl = ct * 16 + lr;
#pragma unroll
        for (int rp = 0; rp < 2; ++rp) {
          int r0 = rp * 2;
          int pos0 = wave * 32 + nt * 16 + lh * 4 + r0;
          float o0 = sigm(accV[nt][ct][r0] + blv[ct]);
          float o1 = sigm(accV[nt][ct][r0 + 1] + blv[ct]);
          unsigned int pk = f2bf2(o0, o1);
          int slot0 = (cl >> 3) ^ (pos0 & 7);
          int slot1 = (cl >> 3) ^ ((pos0 + 1) & 7);
          lds[pos0 * 64 + slot0 * 8 + (cl & 7)] = (unsigned short)pk;
          lds[(pos0 + 1) * 64 + slot1 * 8 + (cl & 7)] = (unsigned short)(pk >> 16);
        }
      }
    __syncthreads();
#pragma unroll
    for (int it = 0; it < 4; ++it) {
      int u = it * 256 + t;
      int pos = u >> 3, ch = u & 7;
      int slot = ch ^ (pos & 7);
      bf8_t v = *(const bf8_t*)&lds[pos * 64 + slot * 8];
      *(bf8_t*)(g3 + (size_t)(p0 + pos) * CC + h * 64 + ch * 8) = v;
    }
  }
}

// ---------------- kB: per-channel GEMM out_pre[c][i][j] = sum_k A[c][i][k]*B[c][j][k]
__global__ __launch_bounds__(256) void kB(const unsigned short* __restrict__ i_s,
                                          const unsigned short* __restrict__ j_s,
                                          float* __restrict__ out_pre) {
  __shared__ unsigned short At[128][32];
  __shared__ unsigned short Bt[128][32];
  int b = blockIdx.x;
  int logical = (b & 7) * 144 + (b >> 3);  // XCD-bijective swizzle (1152 = 8*144)
  int c = logical / 9;
  int tt = logical % 9;
  int i0 = (tt / 3) * 128, j0 = (tt % 3) * 128;
  const unsigned short* Ab = i_s + ((size_t)c * NN + i0) * NN;
  const unsigned short* Bb = j_s + ((size_t)c * NN + j0) * NN;
  int t = threadIdx.x, lane = t & 63, wave = t >> 6;
  int wi = (wave >> 1) * 64, wj = (wave & 1) * 64;
  int lr = lane & 15, lh = lane >> 4;
  int rsub = lane >> 2;
  int ksub = (lane & 3) * 8;

  f32x4_t z4 = {0.f, 0.f, 0.f, 0.f};
  f32x4_t acc[4][4];
#pragma unroll
  for (int mt = 0; mt < 4; ++mt)
#pragma unroll
    for (int nt = 0; nt < 4; ++nt) acc[mt][nt] = z4;

  for (int k0 = 0; k0 < NN; k0 += 32) {
#pragma unroll
    for (int half = 0; half < 2; ++half) {
      int r = half * 64 + wave * 16;
      __builtin_amdgcn_global_load_lds(
          (const __attribute__((address_space(1))) unsigned int*)(Ab + (size_t)(r + rsub) * NN + k0 + ksub),
          (__attribute__((address_space(3))) unsigned int*)&At[r][0], 16, 0, 0);
      __builtin_amdgcn_global_load_lds(
          (const __attribute__((address_space(1))) unsigned int*)(Bb + (size_t)(r + rsub) * NN + k0 + ksub),
          (__attribute__((address_space(3))) unsigned int*)&Bt[r][0], 16, 0, 0);
    }
    __syncthreads();
    bf8_t af2[4], bf2[4];
#pragma unroll
    for (int mt = 0; mt < 4; ++mt) af2[mt] = *(const bf8_t*)&At[wi + mt * 16 + lr][lh * 8];
#pragma unroll
    for (int nt = 0; nt < 4; ++nt) bf2[nt] = *(const bf8_t*)&Bt[wj + nt * 16 + lr][lh * 8];
#pragma unroll
    for (int mt = 0; mt < 4; ++mt)
#pragma unroll
      for (int nt = 0; nt < 4; ++nt) acc[mt][nt] = MFMA16(af2[mt], bf2[nt], acc[mt][nt]);
    __syncthreads();
  }
  float* orow = out_pre + ((size_t)c * NN + (i0 + wi)) * NN + (j0 + wj);
#pragma unroll
  for (int mt = 0; mt < 4; ++mt)
#pragma unroll
    for (int nt = 0; nt < 4; ++nt)
#pragma unroll
      for (int r = 0; r < 4; ++r)
        orow[(size_t)(mt * 16 + lh * 4 + r) * NN + nt * 16 + lr] = acc[mt][nt][r];
}

// ---------------- kC: LN2 + w2 + gate -> out [p][c] fp32 -----------------
__global__ __launch_bounds__(256) void kC(const float* __restrict__ out_pre,
                                          const float* __restrict__ n2g,
                                          const float* __restrict__ n2b,
                                          const unsigned short* __restrict__ w2bf,
                                          const float* __restrict__ b2,
                                          const unsigned short* __restrict__ g3,
                                          float* __restrict__ out) {
  __shared__ unsigned short xs2[128][136];
  int b = blockIdx.x;
  int ii = b / 3, j0 = (b % 3) * 128;
  int t = threadIdx.x, lane = t & 63, wave = t >> 6;
  {
    int pos = t >> 1, half = t & 1;
    const float* src = out_pre + (size_t)half * 64 * NPOS + (size_t)ii * NN + j0 + pos;
    float v[64];
    float s = 0.f;
#pragma unroll
    for (int a2 = 0; a2 < 64; ++a2) { v[a2] = src[(size_t)a2 * NPOS]; s += v[a2]; }
    s += __shfl_xor(s, 1);
    float mu = s * (1.0f / CC);
    float vs = 0.f;
#pragma unroll
    for (int a2 = 0; a2 < 64; ++a2) { float d = v[a2] - mu; vs += d * d; }
    vs += __shfl_xor(vs, 1);
    float rs = rsqrtf(vs * (1.0f / CC) + 1e-5f);
#pragma unroll
    for (int a8 = 0; a8 < 8; ++a8) {
      union { bf8_t v8; unsigned int w[4]; } u;
#pragma unroll
      for (int q = 0; q < 4; ++q) {
        int c0 = half * 64 + a8 * 8 + q * 2;
        float y0 = (v[a8 * 8 + q * 2 + 0] - mu) * rs * n2g[c0] + n2b[c0];
        float y1 = (v[a8 * 8 + q * 2 + 1] - mu) * rs * n2g[c0 + 1] + n2b[c0 + 1];
        u.w[q] = f2bf2(y0, y1);
      }
      *(bf8_t*)&xs2[pos][half * 64 + a8 * 8] = u.v8;
    }
  }
  __syncthreads();
  int lr = lane & 15, lh = lane >> 4;
  bf8_t af2[2][4];
#pragma unroll
  for (int mt = 0; mt < 2; ++mt)
#pragma unroll
    for (int kk = 0; kk < 4; ++kk)
      af2[mt][kk] = *(const bf8_t*)&xs2[wave * 32 + mt * 16 + lr][kk * 32 + lh * 8];
  f32x4_t z4 = {0.f, 0.f, 0.f, 0.f};
  f32x4_t acc[2][8];
#pragma unroll
  for (int mt = 0; mt < 2; ++mt)
#pragma unroll
    for (int nt = 0; nt < 8; ++nt) acc[mt][nt] = z4;
#pragma unroll
  for (int nt = 0; nt < 8; ++nt) {
#pragma unroll
    for (int kk = 0; kk < 4; ++kk) {
      bf8_t bw = *(const bf8_t*)(w2bf + (size_t)(nt * 16 + lr) * CC + kk * 32 + lh * 8);
#pragma unroll
      for (int mt = 0; mt < 2; ++mt) acc[mt][nt] = MFMA16(af2[mt][kk], bw, acc[mt][nt]);
    }
  }
#pragma unroll
  for (int mt = 0; mt < 2; ++mt)
#pragma unroll
    for (int nt = 0; nt < 8; ++nt)
#pragma unroll
      for (int r = 0; r < 4; ++r) {
        int posl = wave * 32 + mt * 16 + lh * 4 + r;
        int c = nt * 16 + lr;
        size_t p = (size_t)ii * NN + j0 + posl;
        float y = acc[mt][nt][r] + b2[c];
        out[p * CC + c] = y * bf2f(g3[p * CC + c]);
      }
}

extern "C" void kernel_launch(void* const* d_in, const int* in_sizes, int n_in,
                              void* d_out, int out_size, void* d_ws, size_t ws_size,
                              hipStream_t stream) {
  (void)in_sizes; (void)n_in; (void)out_size; (void)ws_size;
  const float* x2d  = (const float*)d_in[0];
  const float* n1g  = (const float*)d_in[1];
  const float* n1b  = (const float*)d_in[2];
  const float* n2g  = (const float*)d_in[3];
  const float* n2b  = (const float*)d_in[4];
  const float* w1i  = (const float*)d_in[5];
  const float* b1i  = (const float*)d_in[6];
  const float* w1j  = (const float*)d_in[7];
  const float* b1j  = (const float*)d_in[8];
  const float* w1is = (const float*)d_in[9];
  const float* b1is = (const float*)d_in[10];
  const float* w1js = (const float*)d_in[11];
  const float* b1js = (const float*)d_in[12];
  const float* w2   = (const float*)d_in[13];
  const float* b2   = (const float*)d_in[14];
  const float* w3   = (const float*)d_in[15];
  const float* b3   = (const float*)d_in[16];

  char* ws = (char*)d_ws;
  unsigned short* wcat = (unsigned short*)ws;            // 192 KiB (padded to 256 KiB)
  size_t TELEMS = (size_t)CC * NN * NN;                  // 18,874,368
  unsigned short* i_s  = (unsigned short*)(ws + 262144); // 36 MiB [c][p]
  unsigned short* j_s  = i_s + TELEMS;                   // 36 MiB [c][p]
  unsigned short* g3   = j_s + TELEMS;                   // 36 MiB [p][c]
  unsigned short* x_ln = g3 + TELEMS;                    // 36 MiB [p][c]
  // out_pre (72 MiB fp32) aliases x_ln (+36MB beyond): x_ln dead after kP.
  float* out_pre = (float*)x_ln;
  float* outp = (float*)d_out;

  kW<<<96, 256, 0, stream>>>(w1i, w1is, w1j, w1js, w3, w2, wcat);
  kLN<<<1152, 256, 0, stream>>>(x2d, n1g, n1b, x_ln);
  kP<<<6912, 256, 0, stream>>>(x_ln, wcat, b1i, b1is, b1j, b1js, b3, i_s, j_s, g3);
  kB<<<1152, 256, 0, stream>>>(i_s, j_s, out_pre);
  kC<<<1152, 256, 0, stream>>>(out_pre, n2g, n2b, wcat + 5 * CC * CC, b2, g3, outp);
}

// Round 9
// 195.815 us; speedup vs baseline: 1.1131x; 1.1131x over previous
//
#include <hip/hip_runtime.h>

#define NN 384
#define CC 128
#define NPOS (NN * NN)  // 147456

typedef short bf8_t __attribute__((ext_vector_type(8)));
typedef float f32x4_t __attribute__((ext_vector_type(4)));

#define MFMA16(a, b, c) __builtin_amdgcn_mfma_f32_16x16x32_bf16((a), (b), (c), 0, 0, 0)

__device__ __forceinline__ unsigned short f2bf(float f) {
  unsigned int u = __builtin_bit_cast(unsigned int, f);
  u += 0x7fffu + ((u >> 16) & 1u);  // RNE
  return (unsigned short)(u >> 16);
}
__device__ __forceinline__ float bf2f(unsigned short s) {
  return __builtin_bit_cast(float, ((unsigned int)s) << 16);
}
__device__ __forceinline__ float sigm(float x) { return 1.0f / (1.0f + __expf(-x)); }

// ---------------- kW: fp32 -> bf16 weight concat [768][128] -----------------
__global__ __launch_bounds__(256) void kW(const float* __restrict__ a,
                                          const float* __restrict__ b,
                                          const float* __restrict__ c,
                                          const float* __restrict__ d,
                                          const float* __restrict__ e,
                                          const float* __restrict__ f,
                                          unsigned short* __restrict__ o) {
  int idx = (blockIdx.x * 256 + threadIdx.x) * 4;
  const float* s = f;
  if (idx < 16384) s = a;
  else if (idx < 32768) s = b;
  else if (idx < 49152) s = c;
  else if (idx < 65536) s = d;
  else if (idx < 81920) s = e;
  int off = idx & 16383;
  float4 v = *(const float4*)(s + off);
  o[idx + 0] = f2bf(v.x);
  o[idx + 1] = f2bf(v.y);
  o[idx + 2] = f2bf(v.z);
  o[idx + 3] = f2bf(v.w);
}

// ---------------- kLN: LN1 streaming, x2d fp32 -> x_ln bf16 [pos][c] --------
__global__ __launch_bounds__(256) void kLN(const float* __restrict__ x,
                                           const float* __restrict__ n1g,
                                           const float* __restrict__ n1b,
                                           unsigned short* __restrict__ x_ln) {
  int t = threadIdx.x;
  int pos = blockIdx.x * 128 + (t >> 1);
  int half = t & 1;
  const float* xr = x + (size_t)pos * CC + half * 64;
  float v[64];
  float s = 0.f;
#pragma unroll
  for (int a = 0; a < 16; ++a) {
    float4 f4 = ((const float4*)xr)[a];
    v[4 * a + 0] = f4.x; v[4 * a + 1] = f4.y;
    v[4 * a + 2] = f4.z; v[4 * a + 3] = f4.w;
    s += f4.x + f4.y + f4.z + f4.w;
  }
  s += __shfl_xor(s, 1);
  float mu = s * (1.0f / CC);
  float vs = 0.f;
#pragma unroll
  for (int a = 0; a < 64; ++a) { float d = v[a] - mu; vs += d * d; }
  vs += __shfl_xor(vs, 1);
  float rs = rsqrtf(vs * (1.0f / CC) + 1e-5f);
  unsigned short* dst = x_ln + (size_t)pos * CC + half * 64;
#pragma unroll
  for (int a8 = 0; a8 < 8; ++a8) {
    union { bf8_t v8; unsigned short e[8]; } u;
#pragma unroll
    for (int e = 0; e < 8; ++e) {
      int c = half * 64 + a8 * 8 + e;
      u.e[e] = f2bf((v[a8 * 8 + e] - mu) * rs * n1g[c] + n1b[c]);
    }
    *(bf8_t*)(dst + a8 * 8) = u.v8;
  }
}

// ---------------- kP: projections + gates, one small independent job/block --
// XCD-grouped mapping: the 6 jobs (p,h) of a pos-tile run on the SAME XCD,
// temporally adjacent -> x_ln tile fetched once per XCD L2.
__global__ __launch_bounds__(256, 2) void kP(
    const unsigned short* __restrict__ x_ln, const unsigned short* __restrict__ wcat,
    const float* __restrict__ b1i, const float* __restrict__ b1is,
    const float* __restrict__ b1j, const float* __restrict__ b1js,
    const float* __restrict__ b3v, unsigned short* __restrict__ i_s,
    unsigned short* __restrict__ j_s, unsigned short* __restrict__ g3) {
  __shared__ __align__(16) unsigned short lds[16640];
  // [0,8192): Wv (later gather tile)  [8192,16384): Wg  [16384,16640): bias
  float* bl = (float*)(lds + 16384);

  int b = blockIdx.x;
  int xcd = b & 7, m = b >> 3;
  int tl = m / 6, job = m % 6;
  int pt = xcd * 144 + tl;
  int p = job >> 1, h = job & 1;
  int p0 = pt * 128;
  int t = threadIdx.x, lane = t & 63, wave = t >> 6;
  int lr = lane & 15, lh = lane >> 4;

  // ---- X fragments: direct global->reg ----
  bf8_t xf[2][4];
#pragma unroll
  for (int nt = 0; nt < 2; ++nt)
#pragma unroll
    for (int kk = 0; kk < 4; ++kk)
      xf[nt][kk] = *(const bf8_t*)(x_ln + (size_t)(p0 + wave * 32 + nt * 16 + lr) * CC +
                                   kk * 32 + lh * 8);

  // ---- W staging (pre-swizzled global source, linear LDS dest) ----
  int mV = p * 2;
  const unsigned short* Wv = wcat + (size_t)mV * CC * CC + h * 64 * CC;
#pragma unroll
  for (int it = 0; it < 4; ++it) {
    int u = it * 256 + t;
    int row = u >> 4, sl = u & 15;
    int slg = sl ^ (row & 7);
    __builtin_amdgcn_global_load_lds(
        (const __attribute__((address_space(1))) unsigned int*)(Wv + row * CC + slg * 8),
        (__attribute__((address_space(3))) unsigned int*)(lds + u * 8), 16, 0, 0);
  }
  if (p < 2) {
    const unsigned short* Wg = wcat + (size_t)(mV + 1) * CC * CC + h * 64 * CC;
#pragma unroll
    for (int it = 0; it < 4; ++it) {
      int u = it * 256 + t;
      int row = u >> 4, sl = u & 15;
      int slg = sl ^ (row & 7);
      __builtin_amdgcn_global_load_lds(
          (const __attribute__((address_space(1))) unsigned int*)(Wg + row * CC + slg * 8),
          (__attribute__((address_space(3))) unsigned int*)(lds + 8192 + u * 8), 16, 0, 0);
    }
  }
  // ---- bias: bl[0..63]=V, bl[64..127]=G ----
  {
    const float* bvp = (p == 0) ? b1i : (p == 1) ? b1j : b3v;
    if (t < 16) ((float4*)bl)[t] = ((const float4*)(bvp + h * 64))[t];
    if (p < 2 && t >= 16 && t < 32) {
      const float* bgp = (p == 0) ? b1is : b1js;
      ((float4*)bl)[t] = ((const float4*)(bgp + h * 64))[t - 16];
    }
  }
  __syncthreads();

  // ---- bias prefetch to registers (latency hidden under COMP) ----
  float blv[16], blg[16];
  if (p < 2) {
#pragma unroll
    for (int ct = 0; ct < 4; ++ct)
#pragma unroll
      for (int r = 0; r < 4; ++r) {
        blv[ct * 4 + r] = bl[ct * 16 + lh * 4 + r];
        blg[ct * 4 + r] = bl[64 + ct * 16 + lh * 4 + r];
      }
  } else {
#pragma unroll
    for (int ct = 0; ct < 4; ++ct) blv[ct] = bl[ct * 16 + lr];
  }

  // ---- COMP ----
  f32x4_t z4 = {0.f, 0.f, 0.f, 0.f};
  f32x4_t accV[2][4], accG[2][4];
#pragma unroll
  for (int nt = 0; nt < 2; ++nt)
#pragma unroll
    for (int ct = 0; ct < 4; ++ct) { accV[nt][ct] = z4; accG[nt][ct] = z4; }
#pragma unroll
  for (int ct = 0; ct < 4; ++ct)
#pragma unroll
    for (int kk = 0; kk < 4; ++kk) {
      int rv = ct * 16 + lr;
      int slot = (kk * 4 + lh) ^ (rv & 7);
      bf8_t wv = *(const bf8_t*)&lds[rv * 128 + slot * 8];
      if (p < 2) {
        bf8_t wg = *(const bf8_t*)&lds[8192 + rv * 128 + slot * 8];
#pragma unroll
        for (int nt = 0; nt < 2; ++nt) {
          accV[nt][ct] = MFMA16(wv, xf[nt][kk], accV[nt][ct]);  // D[c][pos]
          accG[nt][ct] = MFMA16(wg, xf[nt][kk], accG[nt][ct]);
        }
      } else {
#pragma unroll
        for (int nt = 0; nt < 2; ++nt)
          accV[nt][ct] = MFMA16(xf[nt][kk], wv, accV[nt][ct]);  // D[pos][c]
      }
    }
  __syncthreads();  // all waves done reading W -> lds[0,8192) becomes gather

  if (p < 2) {
    // gated, gather [64c][128pos] swizzled, store transposed 256B segments
#pragma unroll
    for (int nt = 0; nt < 2; ++nt)
#pragma unroll
      for (int ct = 0; ct < 4; ++ct)
#pragma unroll
        for (int r = 0; r < 4; ++r) {
          int cl = ct * 16 + lh * 4 + r;
          int pos = wave * 32 + nt * 16 + lr;
          float o = (accV[nt][ct][r] + blv[ct * 4 + r]) *
                    sigm(accG[nt][ct][r] + blg[ct * 4 + r]);
          int sw = ((ct * 4 + lh) & 7) << 4;
          lds[cl * 128 + (pos ^ sw)] = f2bf(o);
        }
    __syncthreads();
    unsigned short* dstm = p ? j_s : i_s;
#pragma unroll
    for (int it = 0; it < 4; ++it) {
      int u = it * 256 + t;
      int cl = u >> 4, ch = u & 15;
      int s = (cl >> 2) & 7;
      bf8_t v = *(const bf8_t*)&lds[cl * 128 + ((ch ^ (s << 1)) * 8)];
      *(bf8_t*)(dstm + (size_t)(h * 64 + cl) * NPOS + p0 + ch * 8) = v;
    }
  } else {
    // sigmoid only, gather [128pos][64c] swizzled, store natural 128B segments
#pragma unroll
    for (int nt = 0; nt < 2; ++nt)
#pragma unroll
      for (int ct = 0; ct < 4; ++ct)
#pragma unroll
        for (int r = 0; r < 4; ++r) {
          int pos = wave * 32 + nt * 16 + lh * 4 + r;
          int cl = ct * 16 + lr;
          float o = sigm(accV[nt][ct][r] + blv[ct]);
          int slot = (cl >> 3) ^ (pos & 7);
          lds[pos * 64 + slot * 8 + (cl & 7)] = f2bf(o);
        }
    __syncthreads();
#pragma unroll
    for (int it = 0; it < 4; ++it) {
      int u = it * 256 + t;
      int pos = u >> 3, ch = u & 7;
      int slot = ch ^ (pos & 7);
      bf8_t v = *(const bf8_t*)&lds[pos * 64 + slot * 8];
      *(bf8_t*)(g3 + (size_t)(p0 + pos) * CC + h * 64 + ch * 8) = v;
    }
  }
}

// ---------------- kB: per-channel GEMM out_pre[c][i][j] = sum_k A[c][i][k]*B[c][j][k]
__global__ __launch_bounds__(256) void kB(const unsigned short* __restrict__ i_s,
                                          const unsigned short* __restrict__ j_s,
                                          float* __restrict__ out_pre) {
  __shared__ unsigned short At[128][32];
  __shared__ unsigned short Bt[128][32];
  int b = blockIdx.x;
  int logical = (b & 7) * 144 + (b >> 3);  // XCD-bijective swizzle (1152 = 8*144)
  int c = logical / 9;
  int tt = logical % 9;
  int i0 = (tt / 3) * 128, j0 = (tt % 3) * 128;
  const unsigned short* Ab = i_s + ((size_t)c * NN + i0) * NN;
  const unsigned short* Bb = j_s + ((size_t)c * NN + j0) * NN;
  int t = threadIdx.x, lane = t & 63, wave = t >> 6;
  int wi = (wave >> 1) * 64, wj = (wave & 1) * 64;
  int lr = lane & 15, lh = lane >> 4;
  int rsub = lane >> 2;
  int ksub = (lane & 3) * 8;

  f32x4_t z4 = {0.f, 0.f, 0.f, 0.f};
  f32x4_t acc[4][4];
#pragma unroll
  for (int mt = 0; mt < 4; ++mt)
#pragma unroll
    for (int nt = 0; nt < 4; ++nt) acc[mt][nt] = z4;

  for (int k0 = 0; k0 < NN; k0 += 32) {
#pragma unroll
    for (int half = 0; half < 2; ++half) {
      int r = half * 64 + wave * 16;
      __builtin_amdgcn_global_load_lds(
          (const __attribute__((address_space(1))) unsigned int*)(Ab + (size_t)(r + rsub) * NN + k0 + ksub),
          (__attribute__((address_space(3))) unsigned int*)&At[r][0], 16, 0, 0);
      __builtin_amdgcn_global_load_lds(
          (const __attribute__((address_space(1))) unsigned int*)(Bb + (size_t)(r + rsub) * NN + k0 + ksub),
          (__attribute__((address_space(3))) unsigned int*)&Bt[r][0], 16, 0, 0);
    }
    __syncthreads();
    bf8_t af2[4], bf2[4];
#pragma unroll
    for (int mt = 0; mt < 4; ++mt) af2[mt] = *(const bf8_t*)&At[wi + mt * 16 + lr][lh * 8];
#pragma unroll
    for (int nt = 0; nt < 4; ++nt) bf2[nt] = *(const bf8_t*)&Bt[wj + nt * 16 + lr][lh * 8];
#pragma unroll
    for (int mt = 0; mt < 4; ++mt)
#pragma unroll
      for (int nt = 0; nt < 4; ++nt) acc[mt][nt] = MFMA16(af2[mt], bf2[nt], acc[mt][nt]);
    __syncthreads();
  }
  float* orow = out_pre + ((size_t)c * NN + (i0 + wi)) * NN + (j0 + wj);
#pragma unroll
  for (int mt = 0; mt < 4; ++mt)
#pragma unroll
    for (int nt = 0; nt < 4; ++nt)
#pragma unroll
      for (int r = 0; r < 4; ++r)
        orow[(size_t)(mt * 16 + lh * 4 + r) * NN + nt * 16 + lr] = acc[mt][nt][r];
}

// ---------------- kC: LDS-staged LN2 + w2 + gate -> out [p][c] fp32 ---------
// R8 evidence: 64 scalar strided loads/thread left kC latency-bound (2% Mfma,
// 7% VALU, 20% HBM). Stage the fp32 tile [c][pos] via global_load_lds
// (coalesced 512B channel rows), LN from LDS, overlay bf16 MFMA tile.
__global__ __launch_bounds__(256, 2) void kC(const float* __restrict__ out_pre,
                                             const float* __restrict__ n2g,
                                             const float* __restrict__ n2b,
                                             const unsigned short* __restrict__ w2bf,
                                             const float* __restrict__ b2,
                                             const unsigned short* __restrict__ g3,
                                             float* __restrict__ out) {
  __shared__ __align__(16) float ldsf[16384];   // 64KB: [128 c][128 pos] fp32
  unsigned short* xs2 = (unsigned short*)ldsf;  // overlay after LN: [128 pos][136]
  int b = blockIdx.x;
  int ii = b / 3, j0 = (b % 3) * 128;
  int t = threadIdx.x, lane = t & 63, wave = t >> 6;

  // ---- coalesced stage: out_pre[c][ii][j0..+127] -> ldsf[c][pos] ----
#pragma unroll
  for (int it = 0; it < 16; ++it) {
    int u = it * 256 + t;
    int c = u >> 5, jg = u & 31;
    __builtin_amdgcn_global_load_lds(
        (const __attribute__((address_space(1))) unsigned int*)(out_pre + ((size_t)c * NN + ii) * NN + j0 + jg * 4),
        (__attribute__((address_space(3))) unsigned int*)(ldsf + u * 4), 16, 0, 0);
  }
  __syncthreads();

  {  // LN2 from LDS: 2 threads/pos, 64 channels each; bf16 held in regs
    int pos = t >> 1, half = t & 1;
    float v[64];
    float s = 0.f;
#pragma unroll
    for (int a = 0; a < 64; ++a) { v[a] = ldsf[(half * 64 + a) * 128 + pos]; s += v[a]; }
    s += __shfl_xor(s, 1);
    float mu = s * (1.0f / CC);
    float vs = 0.f;
#pragma unroll
    for (int a = 0; a < 64; ++a) { float d = v[a] - mu; vs += d * d; }
    vs += __shfl_xor(vs, 1);
    float rs = rsqrtf(vs * (1.0f / CC) + 1e-5f);
    union { bf8_t v8[8]; unsigned short e[64]; } u;
#pragma unroll
    for (int a = 0; a < 64; ++a) {
      int c = half * 64 + a;
      u.e[a] = f2bf((v[a] - mu) * rs * n2g[c] + n2b[c]);
    }
    __syncthreads();  // all fp32 LDS reads done -> safe to overlay bf16 tile
#pragma unroll
    for (int a8 = 0; a8 < 8; ++a8)
      *(bf8_t*)&xs2[pos * 136 + half * 64 + a8 * 8] = u.v8[a8];
  }
  __syncthreads();

  int lr = lane & 15, lh = lane >> 4;
  bf8_t af2[2][4];
#pragma unroll
  for (int mt = 0; mt < 2; ++mt)
#pragma unroll
    for (int kk = 0; kk < 4; ++kk)
      af2[mt][kk] = *(const bf8_t*)&xs2[(wave * 32 + mt * 16 + lr) * 136 + kk * 32 + lh * 8];
  f32x4_t z4 = {0.f, 0.f, 0.f, 0.f};
  f32x4_t acc[2][8];
#pragma unroll
  for (int mt = 0; mt < 2; ++mt)
#pragma unroll
    for (int nt = 0; nt < 8; ++nt) acc[mt][nt] = z4;
#pragma unroll
  for (int nt = 0; nt < 8; ++nt) {
#pragma unroll
    for (int kk = 0; kk < 4; ++kk) {
      bf8_t bw = *(const bf8_t*)(w2bf + (size_t)(nt * 16 + lr) * CC + kk * 32 + lh * 8);
#pragma unroll
      for (int mt = 0; mt < 2; ++mt) acc[mt][nt] = MFMA16(af2[mt][kk], bw, acc[mt][nt]);
    }
  }
#pragma unroll
  for (int mt = 0; mt < 2; ++mt)
#pragma unroll
    for (int nt = 0; nt < 8; ++nt)
#pragma unroll
      for (int r = 0; r < 4; ++r) {
        int posl = wave * 32 + mt * 16 + lh * 4 + r;
        int c = nt * 16 + lr;
        size_t p = (size_t)ii * NN + j0 + posl;
        float y = acc[mt][nt][r] + b2[c];
        out[p * CC + c] = y * bf2f(g3[p * CC + c]);
      }
}

extern "C" void kernel_launch(void* const* d_in, const int* in_sizes, int n_in,
                              void* d_out, int out_size, void* d_ws, size_t ws_size,
                              hipStream_t stream) {
  (void)in_sizes; (void)n_in; (void)out_size; (void)ws_size;
  const float* x2d  = (const float*)d_in[0];
  const float* n1g  = (const float*)d_in[1];
  const float* n1b  = (const float*)d_in[2];
  const float* n2g  = (const float*)d_in[3];
  const float* n2b  = (const float*)d_in[4];
  const float* w1i  = (const float*)d_in[5];
  const float* b1i  = (const float*)d_in[6];
  const float* w1j  = (const float*)d_in[7];
  const float* b1j  = (const float*)d_in[8];
  const float* w1is = (const float*)d_in[9];
  const float* b1is = (const float*)d_in[10];
  const float* w1js = (const float*)d_in[11];
  const float* b1js = (const float*)d_in[12];
  const float* w2   = (const float*)d_in[13];
  const float* b2   = (const float*)d_in[14];
  const float* w3   = (const float*)d_in[15];
  const float* b3   = (const float*)d_in[16];

  char* ws = (char*)d_ws;
  unsigned short* wcat = (unsigned short*)ws;            // 192 KiB (padded to 256 KiB)
  size_t TELEMS = (size_t)CC * NN * NN;                  // 18,874,368
  unsigned short* i_s  = (unsigned short*)(ws + 262144); // 36 MiB [c][p]
  unsigned short* j_s  = i_s + TELEMS;                   // 36 MiB [c][p]
  unsigned short* g3   = j_s + TELEMS;                   // 36 MiB [p][c]
  unsigned short* x_ln = g3 + TELEMS;                    // 36 MiB [p][c]
  // out_pre (72 MiB fp32) aliases x_ln (+36MB beyond): x_ln dead after kP.
  float* out_pre = (float*)x_ln;
  float* outp = (float*)d_out;

  kW<<<96, 256, 0, stream>>>(w1i, w1is, w1j, w1js, w3, w2, wcat);
  kLN<<<1152, 256, 0, stream>>>(x2d, n1g, n1b, x_ln);
  kP<<<6912, 256, 0, stream>>>(x_ln, wcat, b1i, b1is, b1j, b1js, b3, i_s, j_s, g3);
  kB<<<1152, 256, 0, stream>>>(i_s, j_s, out_pre);
  kC<<<1152, 256, 0, stream>>>(out_pre, n2g, n2b, wcat + 5 * CC * CC, b2, g3, outp);
}

// Round 10
// 178.438 us; speedup vs baseline: 1.2215x; 1.0974x over previous
//
#include <hip/hip_runtime.h>

#define NN 384
#define CC 128
#define NPOS (NN * NN)  // 147456

typedef short bf8_t __attribute__((ext_vector_type(8)));
typedef float f32x4_t __attribute__((ext_vector_type(4)));

#define MFMA16(a, b, c) __builtin_amdgcn_mfma_f32_16x16x32_bf16((a), (b), (c), 0, 0, 0)

__device__ __forceinline__ unsigned short f2bf(float f) {
  unsigned int u = __builtin_bit_cast(unsigned int, f);
  u += 0x7fffu + ((u >> 16) & 1u);  // RNE
  return (unsigned short)(u >> 16);
}
__device__ __forceinline__ float bf2f(unsigned short s) {
  return __builtin_bit_cast(float, ((unsigned int)s) << 16);
}
__device__ __forceinline__ float sigm(float x) { return 1.0f / (1.0f + __expf(-x)); }

// ---------------- kW: fp32 -> bf16 weight concat [768][128] -----------------
__global__ __launch_bounds__(256) void kW(const float* __restrict__ a,
                                          const float* __restrict__ b,
                                          const float* __restrict__ c,
                                          const float* __restrict__ d,
                                          const float* __restrict__ e,
                                          const float* __restrict__ f,
                                          unsigned short* __restrict__ o) {
  int idx = (blockIdx.x * 256 + threadIdx.x) * 4;
  const float* s = f;
  if (idx < 16384) s = a;
  else if (idx < 32768) s = b;
  else if (idx < 49152) s = c;
  else if (idx < 65536) s = d;
  else if (idx < 81920) s = e;
  int off = idx & 16383;
  float4 v = *(const float4*)(s + off);
  o[idx + 0] = f2bf(v.x);
  o[idx + 1] = f2bf(v.y);
  o[idx + 2] = f2bf(v.z);
  o[idx + 3] = f2bf(v.w);
}

// ---------------- kLN: LN1 streaming, x2d fp32 -> x_ln bf16 [pos][c] --------
__global__ __launch_bounds__(256) void kLN(const float* __restrict__ x,
                                           const float* __restrict__ n1g,
                                           const float* __restrict__ n1b,
                                           unsigned short* __restrict__ x_ln) {
  int t = threadIdx.x;
  int pos = blockIdx.x * 128 + (t >> 1);
  int half = t & 1;
  const float* xr = x + (size_t)pos * CC + half * 64;
  float v[64];
  float s = 0.f;
#pragma unroll
  for (int a = 0; a < 16; ++a) {
    float4 f4 = ((const float4*)xr)[a];
    v[4 * a + 0] = f4.x; v[4 * a + 1] = f4.y;
    v[4 * a + 2] = f4.z; v[4 * a + 3] = f4.w;
    s += f4.x + f4.y + f4.z + f4.w;
  }
  s += __shfl_xor(s, 1);
  float mu = s * (1.0f / CC);
  float vs = 0.f;
#pragma unroll
  for (int a = 0; a < 64; ++a) { float d = v[a] - mu; vs += d * d; }
  vs += __shfl_xor(vs, 1);
  float rs = rsqrtf(vs * (1.0f / CC) + 1e-5f);
  unsigned short* dst = x_ln + (size_t)pos * CC + half * 64;
#pragma unroll
  for (int a8 = 0; a8 < 8; ++a8) {
    union { bf8_t v8; unsigned short e[8]; } u;
#pragma unroll
    for (int e = 0; e < 8; ++e) {
      int c = half * 64 + a8 * 8 + e;
      u.e[e] = f2bf((v[a8 * 8 + e] - mu) * rs * n1g[c] + n1b[c]);
    }
    *(bf8_t*)(dst + a8 * 8) = u.v8;
  }
}

// ---------------- kP: projections + gates, one small independent job/block --
// XCD-grouped mapping: the 6 jobs (p,h) of a pos-tile run on the SAME XCD,
// temporally adjacent -> x_ln tile fetched once per XCD L2 (R9: FETCH 111->19MB).
__global__ __launch_bounds__(256, 2) void kP(
    const unsigned short* __restrict__ x_ln, const unsigned short* __restrict__ wcat,
    const float* __restrict__ b1i, const float* __restrict__ b1is,
    const float* __restrict__ b1j, const float* __restrict__ b1js,
    const float* __restrict__ b3v, unsigned short* __restrict__ i_s,
    unsigned short* __restrict__ j_s, unsigned short* __restrict__ g3) {
  __shared__ __align__(16) unsigned short lds[16640];
  // [0,8192): Wv (later gather tile)  [8192,16384): Wg  [16384,16640): bias
  float* bl = (float*)(lds + 16384);

  int b = blockIdx.x;
  int xcd = b & 7, m = b >> 3;
  int tl = m / 6, job = m % 6;
  int pt = xcd * 144 + tl;
  int p = job >> 1, h = job & 1;
  int p0 = pt * 128;
  int t = threadIdx.x, lane = t & 63, wave = t >> 6;
  int lr = lane & 15, lh = lane >> 4;

  // ---- X fragments: direct global->reg ----
  bf8_t xf[2][4];
#pragma unroll
  for (int nt = 0; nt < 2; ++nt)
#pragma unroll
    for (int kk = 0; kk < 4; ++kk)
      xf[nt][kk] = *(const bf8_t*)(x_ln + (size_t)(p0 + wave * 32 + nt * 16 + lr) * CC +
                                   kk * 32 + lh * 8);

  // ---- W staging (pre-swizzled global source, linear LDS dest) ----
  int mV = p * 2;
  const unsigned short* Wv = wcat + (size_t)mV * CC * CC + h * 64 * CC;
#pragma unroll
  for (int it = 0; it < 4; ++it) {
    int u = it * 256 + t;
    int row = u >> 4, sl = u & 15;
    int slg = sl ^ (row & 7);
    __builtin_amdgcn_global_load_lds(
        (const __attribute__((address_space(1))) unsigned int*)(Wv + row * CC + slg * 8),
        (__attribute__((address_space(3))) unsigned int*)(lds + u * 8), 16, 0, 0);
  }
  if (p < 2) {
    const unsigned short* Wg = wcat + (size_t)(mV + 1) * CC * CC + h * 64 * CC;
#pragma unroll
    for (int it = 0; it < 4; ++it) {
      int u = it * 256 + t;
      int row = u >> 4, sl = u & 15;
      int slg = sl ^ (row & 7);
      __builtin_amdgcn_global_load_lds(
          (const __attribute__((address_space(1))) unsigned int*)(Wg + row * CC + slg * 8),
          (__attribute__((address_space(3))) unsigned int*)(lds + 8192 + u * 8), 16, 0, 0);
    }
  }
  // ---- bias: bl[0..63]=V, bl[64..127]=G ----
  {
    const float* bvp = (p == 0) ? b1i : (p == 1) ? b1j : b3v;
    if (t < 16) ((float4*)bl)[t] = ((const float4*)(bvp + h * 64))[t];
    if (p < 2 && t >= 16 && t < 32) {
      const float* bgp = (p == 0) ? b1is : b1js;
      ((float4*)bl)[t] = ((const float4*)(bgp + h * 64))[t - 16];
    }
  }
  __syncthreads();

  // ---- bias prefetch to registers (latency hidden under COMP) ----
  float blv[16], blg[16];
  if (p < 2) {
#pragma unroll
    for (int ct = 0; ct < 4; ++ct)
#pragma unroll
      for (int r = 0; r < 4; ++r) {
        blv[ct * 4 + r] = bl[ct * 16 + lh * 4 + r];
        blg[ct * 4 + r] = bl[64 + ct * 16 + lh * 4 + r];
      }
  } else {
#pragma unroll
    for (int ct = 0; ct < 4; ++ct) blv[ct] = bl[ct * 16 + lr];
  }

  // ---- COMP ----
  f32x4_t z4 = {0.f, 0.f, 0.f, 0.f};
  f32x4_t accV[2][4], accG[2][4];
#pragma unroll
  for (int nt = 0; nt < 2; ++nt)
#pragma unroll
    for (int ct = 0; ct < 4; ++ct) { accV[nt][ct] = z4; accG[nt][ct] = z4; }
#pragma unroll
  for (int ct = 0; ct < 4; ++ct)
#pragma unroll
    for (int kk = 0; kk < 4; ++kk) {
      int rv = ct * 16 + lr;
      int slot = (kk * 4 + lh) ^ (rv & 7);
      bf8_t wv = *(const bf8_t*)&lds[rv * 128 + slot * 8];
      if (p < 2) {
        bf8_t wg = *(const bf8_t*)&lds[8192 + rv * 128 + slot * 8];
#pragma unroll
        for (int nt = 0; nt < 2; ++nt) {
          accV[nt][ct] = MFMA16(wv, xf[nt][kk], accV[nt][ct]);  // D[c][pos]
          accG[nt][ct] = MFMA16(wg, xf[nt][kk], accG[nt][ct]);
        }
      } else {
#pragma unroll
        for (int nt = 0; nt < 2; ++nt)
          accV[nt][ct] = MFMA16(xf[nt][kk], wv, accV[nt][ct]);  // D[pos][c]
      }
    }
  __syncthreads();  // all waves done reading W -> lds[0,8192) becomes gather

  if (p < 2) {
    // gated, gather [64c][128pos] swizzled, store transposed 256B segments
#pragma unroll
    for (int nt = 0; nt < 2; ++nt)
#pragma unroll
      for (int ct = 0; ct < 4; ++ct)
#pragma unroll
        for (int r = 0; r < 4; ++r) {
          int cl = ct * 16 + lh * 4 + r;
          int pos = wave * 32 + nt * 16 + lr;
          float o = (accV[nt][ct][r] + blv[ct * 4 + r]) *
                    sigm(accG[nt][ct][r] + blg[ct * 4 + r]);
          int sw = ((ct * 4 + lh) & 7) << 4;
          lds[cl * 128 + (pos ^ sw)] = f2bf(o);
        }
    __syncthreads();
    unsigned short* dstm = p ? j_s : i_s;
#pragma unroll
    for (int it = 0; it < 4; ++it) {
      int u = it * 256 + t;
      int cl = u >> 4, ch = u & 15;
      int s = (cl >> 2) & 7;
      bf8_t v = *(const bf8_t*)&lds[cl * 128 + ((ch ^ (s << 1)) * 8)];
      *(bf8_t*)(dstm + (size_t)(h * 64 + cl) * NPOS + p0 + ch * 8) = v;
    }
  } else {
    // sigmoid only, gather [128pos][64c] swizzled, store natural 128B segments
#pragma unroll
    for (int nt = 0; nt < 2; ++nt)
#pragma unroll
      for (int ct = 0; ct < 4; ++ct)
#pragma unroll
        for (int r = 0; r < 4; ++r) {
          int pos = wave * 32 + nt * 16 + lh * 4 + r;
          int cl = ct * 16 + lr;
          float o = sigm(accV[nt][ct][r] + blv[ct]);
          int slot = (cl >> 3) ^ (pos & 7);
          lds[pos * 64 + slot * 8 + (cl & 7)] = f2bf(o);
        }
    __syncthreads();
#pragma unroll
    for (int it = 0; it < 4; ++it) {
      int u = it * 256 + t;
      int pos = u >> 3, ch = u & 7;
      int slot = ch ^ (pos & 7);
      bf8_t v = *(const bf8_t*)&lds[pos * 64 + slot * 8];
      *(bf8_t*)(g3 + (size_t)(p0 + pos) * CC + h * 64 + ch * 8) = v;
    }
  }
}

// ---------------- kB: per-channel GEMM -> out_pre BF16 [c][i][j] ------------
// bf16 output halves kB write traffic (72->36MB) and kC read traffic; the
// intermediate feeds LayerNorm, where bf16's 0.4% rel error is negligible.
__global__ __launch_bounds__(256) void kB(const unsigned short* __restrict__ i_s,
                                          const unsigned short* __restrict__ j_s,
                                          unsigned short* __restrict__ out_pre) {
  __shared__ unsigned short At[128][32];
  __shared__ unsigned short Bt[128][32];
  int b = blockIdx.x;
  int logical = (b & 7) * 144 + (b >> 3);  // XCD-bijective swizzle (1152 = 8*144)
  int c = logical / 9;
  int tt = logical % 9;
  int i0 = (tt / 3) * 128, j0 = (tt % 3) * 128;
  const unsigned short* Ab = i_s + ((size_t)c * NN + i0) * NN;
  const unsigned short* Bb = j_s + ((size_t)c * NN + j0) * NN;
  int t = threadIdx.x, lane = t & 63, wave = t >> 6;
  int wi = (wave >> 1) * 64, wj = (wave & 1) * 64;
  int lr = lane & 15, lh = lane >> 4;
  int rsub = lane >> 2;
  int ksub = (lane & 3) * 8;

  f32x4_t z4 = {0.f, 0.f, 0.f, 0.f};
  f32x4_t acc[4][4];
#pragma unroll
  for (int mt = 0; mt < 4; ++mt)
#pragma unroll
    for (int nt = 0; nt < 4; ++nt) acc[mt][nt] = z4;

  for (int k0 = 0; k0 < NN; k0 += 32) {
#pragma unroll
    for (int half = 0; half < 2; ++half) {
      int r = half * 64 + wave * 16;
      __builtin_amdgcn_global_load_lds(
          (const __attribute__((address_space(1))) unsigned int*)(Ab + (size_t)(r + rsub) * NN + k0 + ksub),
          (__attribute__((address_space(3))) unsigned int*)&At[r][0], 16, 0, 0);
      __builtin_amdgcn_global_load_lds(
          (const __attribute__((address_space(1))) unsigned int*)(Bb + (size_t)(r + rsub) * NN + k0 + ksub),
          (__attribute__((address_space(3))) unsigned int*)&Bt[r][0], 16, 0, 0);
    }
    __syncthreads();
    bf8_t af2[4], bf2[4];
#pragma unroll
    for (int mt = 0; mt < 4; ++mt) af2[mt] = *(const bf8_t*)&At[wi + mt * 16 + lr][lh * 8];
#pragma unroll
    for (int nt = 0; nt < 4; ++nt) bf2[nt] = *(const bf8_t*)&Bt[wj + nt * 16 + lr][lh * 8];
#pragma unroll
    for (int mt = 0; mt < 4; ++mt)
#pragma unroll
      for (int nt = 0; nt < 4; ++nt) acc[mt][nt] = MFMA16(af2[mt], bf2[nt], acc[mt][nt]);
    __syncthreads();
  }
  unsigned short* orow = out_pre + ((size_t)c * NN + (i0 + wi)) * NN + (j0 + wj);
#pragma unroll
  for (int mt = 0; mt < 4; ++mt)
#pragma unroll
    for (int nt = 0; nt < 4; ++nt)
#pragma unroll
      for (int r = 0; r < 4; ++r)
        orow[(size_t)(mt * 16 + lh * 4 + r) * NN + nt * 16 + lr] = f2bf(acc[mt][nt][r]);
}

// ---------------- kC: LDS-staged LN2 + w2 + gate -> out [p][c] fp32 ---------
// Stage bf16 out_pre tile [c][pos] (32KB) via global_load_lds; LN2 from LDS;
// overlay bf16 MFMA tile [pos][136] in the same LDS after reads complete.
__global__ __launch_bounds__(256, 2) void kC(const unsigned short* __restrict__ out_pre,
                                             const float* __restrict__ n2g,
                                             const float* __restrict__ n2b,
                                             const unsigned short* __restrict__ w2bf,
                                             const float* __restrict__ b2,
                                             const unsigned short* __restrict__ g3,
                                             float* __restrict__ out) {
  __shared__ __align__(16) unsigned short ldsu[17408];  // 34KB: stage [128c][128pos] bf16 / overlay [128][136]
  int b = blockIdx.x;
  int ii = b / 3, j0 = (b % 3) * 128;
  int t = threadIdx.x, lane = t & 63, wave = t >> 6;

  // ---- coalesced stage: out_pre[c][ii][j0..+127] (256B/row) -> ldsu[c][pos] ----
#pragma unroll
  for (int it = 0; it < 8; ++it) {
    int u = it * 256 + t;
    int c = u >> 4, jg = u & 15;
    __builtin_amdgcn_global_load_lds(
        (const __attribute__((address_space(1))) unsigned int*)(out_pre + ((size_t)c * NN + ii) * NN + j0 + jg * 8),
        (__attribute__((address_space(3))) unsigned int*)(ldsu + u * 8), 16, 0, 0);
  }
  __syncthreads();

  {  // LN2 from LDS: 2 threads/pos, 64 channels each; bf16 held in regs
    int pos = t >> 1, half = t & 1;
    float v[64];
    float s = 0.f;
#pragma unroll
    for (int a = 0; a < 64; ++a) { v[a] = bf2f(ldsu[(half * 64 + a) * 128 + pos]); s += v[a]; }
    s += __shfl_xor(s, 1);
    float mu = s * (1.0f / CC);
    float vs = 0.f;
#pragma unroll
    for (int a = 0; a < 64; ++a) { float d = v[a] - mu; vs += d * d; }
    vs += __shfl_xor(vs, 1);
    float rs = rsqrtf(vs * (1.0f / CC) + 1e-5f);
    union { bf8_t v8[8]; unsigned short e[64]; } u;
#pragma unroll
    for (int a = 0; a < 64; ++a) {
      int c = half * 64 + a;
      u.e[a] = f2bf((v[a] - mu) * rs * n2g[c] + n2b[c]);
    }
    __syncthreads();  // all bf16 LDS reads done -> safe to overlay MFMA tile
#pragma unroll
    for (int a8 = 0; a8 < 8; ++a8)
      *(bf8_t*)&ldsu[pos * 136 + half * 64 + a8 * 8] = u.v8[a8];
  }
  __syncthreads();

  int lr = lane & 15, lh = lane >> 4;
  bf8_t af2[2][4];
#pragma unroll
  for (int mt = 0; mt < 2; ++mt)
#pragma unroll
    for (int kk = 0; kk < 4; ++kk)
      af2[mt][kk] = *(const bf8_t*)&ldsu[(wave * 32 + mt * 16 + lr) * 136 + kk * 32 + lh * 8];
  f32x4_t z4 = {0.f, 0.f, 0.f, 0.f};
  f32x4_t acc[2][8];
#pragma unroll
  for (int mt = 0; mt < 2; ++mt)
#pragma unroll
    for (int nt = 0; nt < 8; ++nt) acc[mt][nt] = z4;
#pragma unroll
  for (int nt = 0; nt < 8; ++nt) {
#pragma unroll
    for (int kk = 0; kk < 4; ++kk) {
      bf8_t bw = *(const bf8_t*)(w2bf + (size_t)(nt * 16 + lr) * CC + kk * 32 + lh * 8);
#pragma unroll
      for (int mt = 0; mt < 2; ++mt) acc[mt][nt] = MFMA16(af2[mt][kk], bw, acc[mt][nt]);
    }
  }
#pragma unroll
  for (int mt = 0; mt < 2; ++mt)
#pragma unroll
    for (int nt = 0; nt < 8; ++nt)
#pragma unroll
      for (int r = 0; r < 4; ++r) {
        int posl = wave * 32 + mt * 16 + lh * 4 + r;
        int c = nt * 16 + lr;
        size_t p = (size_t)ii * NN + j0 + posl;
        float y = acc[mt][nt][r] + b2[c];
        out[p * CC + c] = y * bf2f(g3[p * CC + c]);
      }
}

extern "C" void kernel_launch(void* const* d_in, const int* in_sizes, int n_in,
                              void* d_out, int out_size, void* d_ws, size_t ws_size,
                              hipStream_t stream) {
  (void)in_sizes; (void)n_in; (void)out_size; (void)ws_size;
  const float* x2d  = (const float*)d_in[0];
  const float* n1g  = (const float*)d_in[1];
  const float* n1b  = (const float*)d_in[2];
  const float* n2g  = (const float*)d_in[3];
  const float* n2b  = (const float*)d_in[4];
  const float* w1i  = (const float*)d_in[5];
  const float* b1i  = (const float*)d_in[6];
  const float* w1j  = (const float*)d_in[7];
  const float* b1j  = (const float*)d_in[8];
  const float* w1is = (const float*)d_in[9];
  const float* b1is = (const float*)d_in[10];
  const float* w1js = (const float*)d_in[11];
  const float* b1js = (const float*)d_in[12];
  const float* w2   = (const float*)d_in[13];
  const float* b2   = (const float*)d_in[14];
  const float* w3   = (const float*)d_in[15];
  const float* b3   = (const float*)d_in[16];

  char* ws = (char*)d_ws;
  unsigned short* wcat = (unsigned short*)ws;            // 192 KiB (padded to 256 KiB)
  size_t TELEMS = (size_t)CC * NN * NN;                  // 18,874,368
  unsigned short* i_s  = (unsigned short*)(ws + 262144); // 36 MiB [c][p]
  unsigned short* j_s  = i_s + TELEMS;                   // 36 MiB [c][p]
  unsigned short* g3   = j_s + TELEMS;                   // 36 MiB [p][c]
  unsigned short* x_ln = g3 + TELEMS;                    // 36 MiB [p][c]
  // out_pre (36 MiB bf16) aliases x_ln: x_ln dead after kP, kB runs after kP.
  unsigned short* out_pre = x_ln;
  float* outp = (float*)d_out;

  kW<<<96, 256, 0, stream>>>(w1i, w1is, w1j, w1js, w3, w2, wcat);
  kLN<<<1152, 256, 0, stream>>>(x2d, n1g, n1b, x_ln);
  kP<<<6912, 256, 0, stream>>>(x_ln, wcat, b1i, b1is, b1j, b1js, b3, i_s, j_s, g3);
  kB<<<1152, 256, 0, stream>>>(i_s, j_s, out_pre);
  kC<<<1152, 256, 0, stream>>>(out_pre, n2g, n2b, wcat + 5 * CC * CC, b2, g3, outp);
}

// Round 11
// 177.989 us; speedup vs baseline: 1.2246x; 1.0025x over previous
//
#include <hip/hip_runtime.h>

#define NN 384
#define CC 128
#define NPOS (NN * NN)  // 147456

typedef short bf8_t __attribute__((ext_vector_type(8)));
typedef float f32x4_t __attribute__((ext_vector_type(4)));

#define MFMA16(a, b, c) __builtin_amdgcn_mfma_f32_16x16x32_bf16((a), (b), (c), 0, 0, 0)

__device__ __forceinline__ unsigned short f2bf(float f) {
  unsigned int u = __builtin_bit_cast(unsigned int, f);
  u += 0x7fffu + ((u >> 16) & 1u);  // RNE
  return (unsigned short)(u >> 16);
}
__device__ __forceinline__ float bf2f(unsigned short s) {
  return __builtin_bit_cast(float, ((unsigned int)s) << 16);
}
// fast sigmoid: v_exp2 + v_rcp (4 VALU) instead of IEEE div (~14 VALU).
// +-1ulp f32 error, invisible after bf16 rounding. (R10: kP is VALU-issue
// bound, ~350/1900 instr per wave were precise-division ceremony.)
__device__ __forceinline__ float sigm(float x) {
  float e = __builtin_amdgcn_exp2f(x * -1.44269504f);
  return __builtin_amdgcn_rcpf(1.0f + e);
}

// ---------------- kW: fp32 -> bf16 weight concat [768][128] -----------------
__global__ __launch_bounds__(256) void kW(const float* __restrict__ a,
                                          const float* __restrict__ b,
                                          const float* __restrict__ c,
                                          const float* __restrict__ d,
                                          const float* __restrict__ e,
                                          const float* __restrict__ f,
                                          unsigned short* __restrict__ o) {
  int idx = (blockIdx.x * 256 + threadIdx.x) * 4;
  const float* s = f;
  if (idx < 16384) s = a;
  else if (idx < 32768) s = b;
  else if (idx < 49152) s = c;
  else if (idx < 65536) s = d;
  else if (idx < 81920) s = e;
  int off = idx & 16383;
  float4 v = *(const float4*)(s + off);
  o[idx + 0] = f2bf(v.x);
  o[idx + 1] = f2bf(v.y);
  o[idx + 2] = f2bf(v.z);
  o[idx + 3] = f2bf(v.w);
}

// ---------------- kLN: LN1 streaming, x2d fp32 -> x_ln bf16 [pos][c] --------
__global__ __launch_bounds__(256) void kLN(const float* __restrict__ x,
                                           const float* __restrict__ n1g,
                                           const float* __restrict__ n1b,
                                           unsigned short* __restrict__ x_ln) {
  int t = threadIdx.x;
  int pos = blockIdx.x * 128 + (t >> 1);
  int half = t & 1;
  const float* xr = x + (size_t)pos * CC + half * 64;
  float v[64];
  float s = 0.f;
#pragma unroll
  for (int a = 0; a < 16; ++a) {
    float4 f4 = ((const float4*)xr)[a];
    v[4 * a + 0] = f4.x; v[4 * a + 1] = f4.y;
    v[4 * a + 2] = f4.z; v[4 * a + 3] = f4.w;
    s += f4.x + f4.y + f4.z + f4.w;
  }
  s += __shfl_xor(s, 1);
  float mu = s * (1.0f / CC);
  float vs = 0.f;
#pragma unroll
  for (int a = 0; a < 64; ++a) { float d = v[a] - mu; vs += d * d; }
  vs += __shfl_xor(vs, 1);
  float rs = rsqrtf(vs * (1.0f / CC) + 1e-5f);
  unsigned short* dst = x_ln + (size_t)pos * CC + half * 64;
#pragma unroll
  for (int a8 = 0; a8 < 8; ++a8) {
    union { bf8_t v8; unsigned short e[8]; } u;
#pragma unroll
    for (int e = 0; e < 8; ++e) {
      int c = half * 64 + a8 * 8 + e;
      u.e[e] = f2bf((v[a8 * 8 + e] - mu) * rs * n1g[c] + n1b[c]);
    }
    *(bf8_t*)(dst + a8 * 8) = u.v8;
  }
}

// ---------------- kP: projections + gates, one small independent job/block --
// XCD-grouped mapping: the 6 jobs (p,h) of a pos-tile run on the SAME XCD,
// temporally adjacent -> x_ln tile fetched once per XCD L2 (R9: FETCH 111->19MB).
__global__ __launch_bounds__(256, 2) void kP(
    const unsigned short* __restrict__ x_ln, const unsigned short* __restrict__ wcat,
    const float* __restrict__ b1i, const float* __restrict__ b1is,
    const float* __restrict__ b1j, const float* __restrict__ b1js,
    const float* __restrict__ b3v, unsigned short* __restrict__ i_s,
    unsigned short* __restrict__ j_s, unsigned short* __restrict__ g3) {
  __shared__ __align__(16) unsigned short lds[16640];
  // [0,8192): Wv (later gather tile)  [8192,16384): Wg  [16384,16640): bias
  float* bl = (float*)(lds + 16384);

  int b = blockIdx.x;
  int xcd = b & 7, m = b >> 3;
  int tl = m / 6, job = m % 6;
  int pt = xcd * 144 + tl;
  int p = job >> 1, h = job & 1;
  int p0 = pt * 128;
  int t = threadIdx.x, lane = t & 63, wave = t >> 6;
  int lr = lane & 15, lh = lane >> 4;

  // ---- X fragments: direct global->reg ----
  bf8_t xf[2][4];
#pragma unroll
  for (int nt = 0; nt < 2; ++nt)
#pragma unroll
    for (int kk = 0; kk < 4; ++kk)
      xf[nt][kk] = *(const bf8_t*)(x_ln + (size_t)(p0 + wave * 32 + nt * 16 + lr) * CC +
                                   kk * 32 + lh * 8);

  // ---- W staging (pre-swizzled global source, linear LDS dest) ----
  int mV = p * 2;
  const unsigned short* Wv = wcat + (size_t)mV * CC * CC + h * 64 * CC;
#pragma unroll
  for (int it = 0; it < 4; ++it) {
    int u = it * 256 + t;
    int row = u >> 4, sl = u & 15;
    int slg = sl ^ (row & 7);
    __builtin_amdgcn_global_load_lds(
        (const __attribute__((address_space(1))) unsigned int*)(Wv + row * CC + slg * 8),
        (__attribute__((address_space(3))) unsigned int*)(lds + u * 8), 16, 0, 0);
  }
  if (p < 2) {
    const unsigned short* Wg = wcat + (size_t)(mV + 1) * CC * CC + h * 64 * CC;
#pragma unroll
    for (int it = 0; it < 4; ++it) {
      int u = it * 256 + t;
      int row = u >> 4, sl = u & 15;
      int slg = sl ^ (row & 7);
      __builtin_amdgcn_global_load_lds(
          (const __attribute__((address_space(1))) unsigned int*)(Wg + row * CC + slg * 8),
          (__attribute__((address_space(3))) unsigned int*)(lds + 8192 + u * 8), 16, 0, 0);
    }
  }
  // ---- bias: bl[0..63]=V, bl[64..127]=G ----
  {
    const float* bvp = (p == 0) ? b1i : (p == 1) ? b1j : b3v;
    if (t < 16) ((float4*)bl)[t] = ((const float4*)(bvp + h * 64))[t];
    if (p < 2 && t >= 16 && t < 32) {
      const float* bgp = (p == 0) ? b1is : b1js;
      ((float4*)bl)[t] = ((const float4*)(bgp + h * 64))[t - 16];
    }
  }
  __syncthreads();

  // ---- bias prefetch to registers (latency hidden under COMP) ----
  float blv[16], blg[16];
  if (p < 2) {
#pragma unroll
    for (int ct = 0; ct < 4; ++ct)
#pragma unroll
      for (int r = 0; r < 4; ++r) {
        blv[ct * 4 + r] = bl[ct * 16 + lh * 4 + r];
        blg[ct * 4 + r] = bl[64 + ct * 16 + lh * 4 + r];
      }
  } else {
#pragma unroll
    for (int ct = 0; ct < 4; ++ct) blv[ct] = bl[ct * 16 + lr];
  }

  // ---- COMP ----
  f32x4_t z4 = {0.f, 0.f, 0.f, 0.f};
  f32x4_t accV[2][4], accG[2][4];
#pragma unroll
  for (int nt = 0; nt < 2; ++nt)
#pragma unroll
    for (int ct = 0; ct < 4; ++ct) { accV[nt][ct] = z4; accG[nt][ct] = z4; }
#pragma unroll
  for (int ct = 0; ct < 4; ++ct)
#pragma unroll
    for (int kk = 0; kk < 4; ++kk) {
      int rv = ct * 16 + lr;
      int slot = (kk * 4 + lh) ^ (rv & 7);
      bf8_t wv = *(const bf8_t*)&lds[rv * 128 + slot * 8];
      if (p < 2) {
        bf8_t wg = *(const bf8_t*)&lds[8192 + rv * 128 + slot * 8];
#pragma unroll
        for (int nt = 0; nt < 2; ++nt) {
          accV[nt][ct] = MFMA16(wv, xf[nt][kk], accV[nt][ct]);  // D[c][pos]
          accG[nt][ct] = MFMA16(wg, xf[nt][kk], accG[nt][ct]);
        }
      } else {
#pragma unroll
        for (int nt = 0; nt < 2; ++nt)
          accV[nt][ct] = MFMA16(xf[nt][kk], wv, accV[nt][ct]);  // D[pos][c]
      }
    }
  __syncthreads();  // all waves done reading W -> lds[0,8192) becomes gather

  if (p < 2) {
    // gated, gather [64c][128pos] swizzled, store transposed 256B segments
#pragma unroll
    for (int nt = 0; nt < 2; ++nt)
#pragma unroll
      for (int ct = 0; ct < 4; ++ct)
#pragma unroll
        for (int r = 0; r < 4; ++r) {
          int cl = ct * 16 + lh * 4 + r;
          int pos = wave * 32 + nt * 16 + lr;
          float o = (accV[nt][ct][r] + blv[ct * 4 + r]) *
                    sigm(accG[nt][ct][r] + blg[ct * 4 + r]);
          int sw = ((ct * 4 + lh) & 7) << 4;
          lds[cl * 128 + (pos ^ sw)] = f2bf(o);
        }
    __syncthreads();
    unsigned short* dstm = p ? j_s : i_s;
#pragma unroll
    for (int it = 0; it < 4; ++it) {
      int u = it * 256 + t;
      int cl = u >> 4, ch = u & 15;
      int s = (cl >> 2) & 7;
      bf8_t v = *(const bf8_t*)&lds[cl * 128 + ((ch ^ (s << 1)) * 8)];
      *(bf8_t*)(dstm + (size_t)(h * 64 + cl) * NPOS + p0 + ch * 8) = v;
    }
  } else {
    // sigmoid only, gather [128pos][64c] swizzled, store natural 128B segments
#pragma unroll
    for (int nt = 0; nt < 2; ++nt)
#pragma unroll
      for (int ct = 0; ct < 4; ++ct)
#pragma unroll
        for (int r = 0; r < 4; ++r) {
          int pos = wave * 32 + nt * 16 + lh * 4 + r;
          int cl = ct * 16 + lr;
          float o = sigm(accV[nt][ct][r] + blv[ct]);
          int slot = (cl >> 3) ^ (pos & 7);
          lds[pos * 64 + slot * 8 + (cl & 7)] = f2bf(o);
        }
    __syncthreads();
#pragma unroll
    for (int it = 0; it < 4; ++it) {
      int u = it * 256 + t;
      int pos = u >> 3, ch = u & 7;
      int slot = ch ^ (pos & 7);
      bf8_t v = *(const bf8_t*)&lds[pos * 64 + slot * 8];
      *(bf8_t*)(g3 + (size_t)(p0 + pos) * CC + h * 64 + ch * 8) = v;
    }
  }
}

// ---------------- kB: per-channel GEMM -> out_pre BF16 [c][i][j] ------------
__global__ __launch_bounds__(256) void kB(const unsigned short* __restrict__ i_s,
                                          const unsigned short* __restrict__ j_s,
                                          unsigned short* __restrict__ out_pre) {
  __shared__ unsigned short At[128][32];
  __shared__ unsigned short Bt[128][32];
  int b = blockIdx.x;
  int logical = (b & 7) * 144 + (b >> 3);  // XCD-bijective swizzle (1152 = 8*144)
  int c = logical / 9;
  int tt = logical % 9;
  int i0 = (tt / 3) * 128, j0 = (tt % 3) * 128;
  const unsigned short* Ab = i_s + ((size_t)c * NN + i0) * NN;
  const unsigned short* Bb = j_s + ((size_t)c * NN + j0) * NN;
  int t = threadIdx.x, lane = t & 63, wave = t >> 6;
  int wi = (wave >> 1) * 64, wj = (wave & 1) * 64;
  int lr = lane & 15, lh = lane >> 4;
  int rsub = lane >> 2;
  int ksub = (lane & 3) * 8;

  f32x4_t z4 = {0.f, 0.f, 0.f, 0.f};
  f32x4_t acc[4][4];
#pragma unroll
  for (int mt = 0; mt < 4; ++mt)
#pragma unroll
    for (int nt = 0; nt < 4; ++nt) acc[mt][nt] = z4;

  for (int k0 = 0; k0 < NN; k0 += 32) {
#pragma unroll
    for (int half = 0; half < 2; ++half) {
      int r = half * 64 + wave * 16;
      __builtin_amdgcn_global_load_lds(
          (const __attribute__((address_space(1))) unsigned int*)(Ab + (size_t)(r + rsub) * NN + k0 + ksub),
          (__attribute__((address_space(3))) unsigned int*)&At[r][0], 16, 0, 0);
      __builtin_amdgcn_global_load_lds(
          (const __attribute__((address_space(1))) unsigned int*)(Bb + (size_t)(r + rsub) * NN + k0 + ksub),
          (__attribute__((address_space(3))) unsigned int*)&Bt[r][0], 16, 0, 0);
    }
    __syncthreads();
    bf8_t af2[4], bf2[4];
#pragma unroll
    for (int mt = 0; mt < 4; ++mt) af2[mt] = *(const bf8_t*)&At[wi + mt * 16 + lr][lh * 8];
#pragma unroll
    for (int nt = 0; nt < 4; ++nt) bf2[nt] = *(const bf8_t*)&Bt[wj + nt * 16 + lr][lh * 8];
#pragma unroll
    for (int mt = 0; mt < 4; ++mt)
#pragma unroll
      for (int nt = 0; nt < 4; ++nt) acc[mt][nt] = MFMA16(af2[mt], bf2[nt], acc[mt][nt]);
    __syncthreads();
  }
  unsigned short* orow = out_pre + ((size_t)c * NN + (i0 + wi)) * NN + (j0 + wj);
#pragma unroll
  for (int mt = 0; mt < 4; ++mt)
#pragma unroll
    for (int nt = 0; nt < 4; ++nt)
#pragma unroll
      for (int r = 0; r < 4; ++r)
        orow[(size_t)(mt * 16 + lh * 4 + r) * NN + nt * 16 + lr] = f2bf(acc[mt][nt][r]);
}

// ---------------- kC: LDS-staged LN2 + w2 + gate -> out [p][c] fp32 ---------
__global__ __launch_bounds__(256, 2) void kC(const unsigned short* __restrict__ out_pre,
                                             const float* __restrict__ n2g,
                                             const float* __restrict__ n2b,
                                             const unsigned short* __restrict__ w2bf,
                                             const float* __restrict__ b2,
                                             const unsigned short* __restrict__ g3,
                                             float* __restrict__ out) {
  __shared__ __align__(16) unsigned short ldsu[17408];  // 34KB: stage [128c][128pos] bf16 / overlay [128][136]
  int b = blockIdx.x;
  int ii = b / 3, j0 = (b % 3) * 128;
  int t = threadIdx.x, lane = t & 63, wave = t >> 6;

  // ---- coalesced stage: out_pre[c][ii][j0..+127] (256B/row) -> ldsu[c][pos] ----
#pragma unroll
  for (int it = 0; it < 8; ++it) {
    int u = it * 256 + t;
    int c = u >> 4, jg = u & 15;
    __builtin_amdgcn_global_load_lds(
        (const __attribute__((address_space(1))) unsigned int*)(out_pre + ((size_t)c * NN + ii) * NN + j0 + jg * 8),
        (__attribute__((address_space(3))) unsigned int*)(ldsu + u * 8), 16, 0, 0);
  }
  __syncthreads();

  {  // LN2 from LDS: 2 threads/pos, 64 channels each; bf16 held in regs
    int pos = t >> 1, half = t & 1;
    float v[64];
    float s = 0.f;
#pragma unroll
    for (int a = 0; a < 64; ++a) { v[a] = bf2f(ldsu[(half * 64 + a) * 128 + pos]); s += v[a]; }
    s += __shfl_xor(s, 1);
    float mu = s * (1.0f / CC);
    float vs = 0.f;
#pragma unroll
    for (int a = 0; a < 64; ++a) { float d = v[a] - mu; vs += d * d; }
    vs += __shfl_xor(vs, 1);
    float rs = rsqrtf(vs * (1.0f / CC) + 1e-5f);
    union { bf8_t v8[8]; unsigned short e[64]; } u;
#pragma unroll
    for (int a = 0; a < 64; ++a) {
      int c = half * 64 + a;
      u.e[a] = f2bf((v[a] - mu) * rs * n2g[c] + n2b[c]);
    }
    __syncthreads();  // all bf16 LDS reads done -> safe to overlay MFMA tile
#pragma unroll
    for (int a8 = 0; a8 < 8; ++a8)
      *(bf8_t*)&ldsu[pos * 136 + half * 64 + a8 * 8] = u.v8[a8];
  }
  __syncthreads();

  int lr = lane & 15, lh = lane >> 4;
  bf8_t af2[2][4];
#pragma unroll
  for (int mt = 0; mt < 2; ++mt)
#pragma unroll
    for (int kk = 0; kk < 4; ++kk)
      af2[mt][kk] = *(const bf8_t*)&ldsu[(wave * 32 + mt * 16 + lr) * 136 + kk * 32 + lh * 8];
  f32x4_t z4 = {0.f, 0.f, 0.f, 0.f};
  f32x4_t acc[2][8];
#pragma unroll
  for (int mt = 0; mt < 2; ++mt)
#pragma unroll
    for (int nt = 0; nt < 8; ++nt) acc[mt][nt] = z4;
#pragma unroll
  for (int nt = 0; nt < 8; ++nt) {
#pragma unroll
    for (int kk = 0; kk < 4; ++kk) {
      bf8_t bw = *(const bf8_t*)(w2bf + (size_t)(nt * 16 + lr) * CC + kk * 32 + lh * 8);
#pragma unroll
      for (int mt = 0; mt < 2; ++mt) acc[mt][nt] = MFMA16(af2[mt][kk], bw, acc[mt][nt]);
    }
  }
#pragma unroll
  for (int mt = 0; mt < 2; ++mt)
#pragma unroll
    for (int nt = 0; nt < 8; ++nt)
#pragma unroll
      for (int r = 0; r < 4; ++r) {
        int posl = wave * 32 + mt * 16 + lh * 4 + r;
        int c = nt * 16 + lr;
        size_t p = (size_t)ii * NN + j0 + posl;
        float y = acc[mt][nt][r] + b2[c];
        out[p * CC + c] = y * bf2f(g3[p * CC + c]);
      }
}

extern "C" void kernel_launch(void* const* d_in, const int* in_sizes, int n_in,
                              void* d_out, int out_size, void* d_ws, size_t ws_size,
                              hipStream_t stream) {
  (void)in_sizes; (void)n_in; (void)out_size; (void)ws_size;
  const float* x2d  = (const float*)d_in[0];
  const float* n1g  = (const float*)d_in[1];
  const float* n1b  = (const float*)d_in[2];
  const float* n2g  = (const float*)d_in[3];
  const float* n2b  = (const float*)d_in[4];
  const float* w1i  = (const float*)d_in[5];
  const float* b1i  = (const float*)d_in[6];
  const float* w1j  = (const float*)d_in[7];
  const float* b1j  = (const float*)d_in[8];
  const float* w1is = (const float*)d_in[9];
  const float* b1is = (const float*)d_in[10];
  const float* w1js = (const float*)d_in[11];
  const float* b1js = (const float*)d_in[12];
  const float* w2   = (const float*)d_in[13];
  const float* b2   = (const float*)d_in[14];
  const float* w3   = (const float*)d_in[15];
  const float* b3   = (const float*)d_in[16];

  char* ws = (char*)d_ws;
  unsigned short* wcat = (unsigned short*)ws;            // 192 KiB (padded to 256 KiB)
  size_t TELEMS = (size_t)CC * NN * NN;                  // 18,874,368
  unsigned short* i_s  = (unsigned short*)(ws + 262144); // 36 MiB [c][p]
  unsigned short* j_s  = i_s + TELEMS;                   // 36 MiB [c][p]
  unsigned short* g3   = j_s + TELEMS;                   // 36 MiB [p][c]
  unsigned short* x_ln = g3 + TELEMS;                    // 36 MiB [p][c]
  // out_pre (36 MiB bf16) aliases x_ln: x_ln dead after kP, kB runs after kP.
  unsigned short* out_pre = x_ln;
  float* outp = (float*)d_out;

  kW<<<96, 256, 0, stream>>>(w1i, w1is, w1j, w1js, w3, w2, wcat);
  kLN<<<1152, 256, 0, stream>>>(x2d, n1g, n1b, x_ln);
  kP<<<6912, 256, 0, stream>>>(x_ln, wcat, b1i, b1is, b1j, b1js, b3, i_s, j_s, g3);
  kB<<<1152, 256, 0, stream>>>(i_s, j_s, out_pre);
  kC<<<1152, 256, 0, stream>>>(out_pre, n2g, n2b, wcat + 5 * CC * CC, b2, g3, outp);
}